// Round 5
// baseline (1475.017 us; speedup 1.0000x reference)
//
#include <hip/hip_runtime.h>
#include <hip/hip_bf16.h>

// LSTM_autoreg for MI355X.  R3: kernel split to kill the Wih2 L2-BW wall.
// R2 diagnosis: phase C streamed 288 KB of Wih2 per block per level (4.4 GB of
// load traffic, ~56 B/cyc/CU L2 ceiling) -> 1.4 ms BW wall. Fix: hoist
// xg2 = hs1 @ Wih2.T out of the recurrence into a dense GEMM (K2) where each
// weight byte is reused over 128 rows; recurrent kernel K3 initializes MFMA
// accumulators straight from xg2 stored in fragment layout (fp32, bitwise-
// equivalent math). Level-range halved to bound ws (xg2 buffer reused).

#define DEV static __device__ __forceinline__

typedef __attribute__((ext_vector_type(8))) short bf16x8;
typedef __attribute__((ext_vector_type(4))) float f32x4;

DEV unsigned short f2bf(float f) {
  unsigned int u = __builtin_bit_cast(unsigned int, f);
  unsigned int r = (u + 0x7fffu + ((u >> 16) & 1u)) >> 16;
  return (unsigned short)r;
}
DEV float bf2f(unsigned short s) {
  return __builtin_bit_cast(float, ((unsigned int)s) << 16);
}
DEV float sigm(float x) {
  float e = __builtin_amdgcn_exp2f(-1.44269504089f * x);
  return __builtin_amdgcn_rcpf(1.0f + e);
}
DEV float tanhf_(float x) {
  float e = __builtin_amdgcn_exp2f(2.88539008178f * x);
  return 1.0f - 2.0f * __builtin_amdgcn_rcpf(1.0f + e);
}

// ---- packed fragment layout in d_ws (ushort/bf16) ----
// frag-group index rest = segbase + kk*48 + nt ; element = rest*512 + lane*8 + j
// seg B1  (rest   0..335): [Whh1 | Wih1 | b1] K=224 (7 kk-groups)
// seg B2H (rest 336..623): Whh2 K=192 (6 kk)
// seg B2X (rest 624..911): Wih2 K=192 (6 kk)
#define SEG_B2H 336
#define SEG_B2X 624
#define PACK_TOTAL (912 * 512)

// ---- workspace layout (bytes) ----
#define HS1_OFF   (1u << 20)                 // hs1 / hs2 (shared, 94.37 MB)
#define HS1_BYTES 94371840u
#define XG2_OFF   100663296u                 // 96 MB; xg2 half, fp32 frag layout
#define XG2_BYTES 377487360u                 // 4096*30*768*4
#define CWS_OFF   478150656u                 // c-state checkpoint
#define CWS_BYTES 3145728u
#define NEED_FULL (CWS_OFF + CWS_BYTES)      // ~459 MiB
#define NEED_MIN  (HS1_OFF + HS1_BYTES)

__global__ void pack_kernel(const float* __restrict__ Wih1,
                            const float* __restrict__ Whh1,
                            const float* __restrict__ b1,
                            const float* __restrict__ Wih2,
                            const float* __restrict__ Whh2,
                            unsigned short* __restrict__ pw) {
  int idx = blockIdx.x * 256 + threadIdx.x;          // 0..466943
  int j = idx & 7;
  int lane = (idx >> 3) & 63;
  int rest = idx >> 9;
  int n, k; float v;
  if (rest < SEG_B2H) {
    int kk = rest / 48, nt = rest % 48;
    n = nt * 16 + (lane & 15);
    k = kk * 32 + (lane >> 4) * 8 + j;               // 0..223
    if (k < 192) v = Whh1[n * 192 + k];
    else { int t = k - 192; v = (t < 31) ? Wih1[n * 31 + t] : b1[n]; }
  } else if (rest < SEG_B2X) {
    int r2 = rest - SEG_B2H; int kk = r2 / 48, nt = r2 % 48;
    n = nt * 16 + (lane & 15);
    k = kk * 32 + (lane >> 4) * 8 + j;
    v = Whh2[n * 192 + k];
  } else {
    int r2 = rest - SEG_B2X; int kk = r2 / 48, nt = r2 % 48;
    n = nt * 16 + (lane & 15);
    k = kk * 32 + (lane >> 4) * 8 + j;
    v = Wih2[n * 192 + k];
  }
  pw[idx] = f2bf(v);
}

// ================= K1: LSTM1 recurrence (levels 59->0), store hs1 ============
__global__ __launch_bounds__(512, 2) void k1_lstm1(
    const float* __restrict__ xlev, const float* __restrict__ xsfc,
    const float* __restrict__ hmem,
    const float* __restrict__ xmean_lev, const float* __restrict__ xdiv_lev,
    const float* __restrict__ xmean_sca, const float* __restrict__ xdiv_sca,
    const float* __restrict__ Wsfc1, const float* __restrict__ bsfc1,
    const float* __restrict__ Wsfc2, const float* __restrict__ bsfc2,
    const unsigned short* __restrict__ pw,
    unsigned short* __restrict__ hs1g) {

  __shared__ float g_lds[16 * 772];
  __shared__ __align__(16) unsigned short a_lds[16 * 392];
  __shared__ float misc[16 * 24];

  const int tid = threadIdx.x;
  const int lane = tid & 63;
  const int wv = tid >> 6;
  const int bid = blockIdx.x;
  const int r0 = bid * 16;

  int erow[6], ecol[6];
  #pragma unroll
  for (int e = 0; e < 6; ++e) { int idx = tid + 512 * e; erow[e] = idx / 192; ecol[e] = idx % 192; }

  if (tid < 384) {
    int r = tid / 24, j = tid % 24;
    misc[tid] = (xsfc[(r0 + r) * 24 + j] - xmean_sca[j]) / xdiv_sca[j];
  }
  __syncthreads();

  float c[6];
  #pragma unroll
  for (int e = 0; e < 6; ++e) {
    int row = erow[e], col = ecol[e];
    float a1 = bsfc1[col], a2 = bsfc2[col];
    for (int k = 0; k < 24; ++k) {
      float s = misc[row * 24 + k];
      a1 = fmaf(s, Wsfc1[col * 24 + k], a1);
      a2 = fmaf(s, Wsfc2[col * 24 + k], a2);
    }
    a_lds[row * 392 + col] = f2bf(tanhf_(a1));
    c[e] = tanhf_(a2);
  }

  bf16x8 w1[7][6];
  #pragma unroll
  for (int kk = 0; kk < 7; ++kk)
    #pragma unroll
    for (int nt = 0; nt < 6; ++nt)
      w1[kk][nt] = *(const bf16x8*)&pw[((kk * 48 + wv * 6 + nt) * 64 + lane) * 8];

  const int xr = tid >> 5, xj = tid & 31;
  float xraw = 0.f;
  if (xj < 15)      xraw = __builtin_nontemporal_load(&xlev[((r0 + xr) * 60 + 59) * 15 + xj]);
  else if (xj < 31) xraw = __builtin_nontemporal_load(&hmem[((r0 + xr) * 60 + 59) * 16 + (xj - 15)]);

  for (int l = 59; l >= 0; --l) {
    {
      float v;
      if (xj < 15)      v = (xraw - xmean_lev[l * 15 + xj]) / xdiv_lev[l * 15 + xj];
      else if (xj < 31) v = xraw;
      else              v = 1.0f;
      a_lds[xr * 392 + 192 + xj] = f2bf(v);
    }
    if (l > 0) {
      if (xj < 15)      xraw = __builtin_nontemporal_load(&xlev[((r0 + xr) * 60 + l - 1) * 15 + xj]);
      else if (xj < 31) xraw = __builtin_nontemporal_load(&hmem[((r0 + xr) * 60 + l - 1) * 16 + (xj - 15)]);
    }
    __syncthreads();

    f32x4 acc[6];
    #pragma unroll
    for (int nt = 0; nt < 6; ++nt) acc[nt] = (f32x4){0.f, 0.f, 0.f, 0.f};
    #pragma unroll
    for (int kk = 0; kk < 7; ++kk) {
      const bf16x8 af = *(const bf16x8*)&a_lds[(lane & 15) * 392 + kk * 32 + (lane >> 4) * 8];
      #pragma unroll
      for (int nt = 0; nt < 6; ++nt)
        acc[nt] = __builtin_amdgcn_mfma_f32_16x16x32_bf16(af, w1[kk][nt], acc[nt], 0, 0, 0);
    }
    #pragma unroll
    for (int nt = 0; nt < 6; ++nt)
      #pragma unroll
      for (int q = 0; q < 4; ++q)
        g_lds[((lane >> 4) * 4 + q) * 772 + wv * 96 + nt * 16 + (lane & 15)] = acc[nt][q];
    __syncthreads();

    #pragma unroll
    for (int e = 0; e < 6; ++e) {
      int row = erow[e], col = ecol[e];
      float gi = g_lds[row * 772 + col];
      float gf = g_lds[row * 772 + 192 + col];
      float gg = g_lds[row * 772 + 384 + col];
      float go = g_lds[row * 772 + 576 + col];
      c[e] = sigm(gf) * c[e] + sigm(gi) * tanhf_(gg);
      float hv = sigm(go) * tanhf_(c[e]);
      unsigned short hb = f2bf(hv);
      a_lds[row * 392 + col] = hb;
      __builtin_nontemporal_store(hb, &hs1g[(size_t)(bid * 60 + l) * 3072 + tid + 512 * e]);
    }
  }
}

// ================= K2: xg2 = hs1 @ Wih2.T + b2, fp32 fragment layout =========
// grid 960 blocks; block g covers 8 tiles p2 = 8g..8g+7; p2 = b3*30 + (l-l0).
__global__ __launch_bounds__(512, 2) void k2_xg2(
    const unsigned short* __restrict__ pw,
    const unsigned short* __restrict__ hs1g,
    const float* __restrict__ b2,
    float* __restrict__ xg2, int l0) {

  __shared__ __align__(16) unsigned short a2[8 * 16 * 200];   // padded stride 200

  const int tid = threadIdx.x;
  const int lane = tid & 63;
  const int wv = tid >> 6;
  const int g = blockIdx.x;

  bf16x8 wb[6][6];
  #pragma unroll
  for (int kk = 0; kk < 6; ++kk)
    #pragma unroll
    for (int nt = 0; nt < 6; ++nt)
      wb[kk][nt] = *(const bf16x8*)&pw[((SEG_B2X + kk * 48 + wv * 6 + nt) * 64 + lane) * 8];

  float b2v[6];
  #pragma unroll
  for (int nt = 0; nt < 6; ++nt) b2v[nt] = b2[wv * 96 + nt * 16 + (lane & 15)];

  // stage 8 hs1 tiles -> LDS (48 KB, 6x16B per thread)
  #pragma unroll
  for (int i = 0; i < 6; ++i) {
    int flat16 = tid + 512 * i;            // 0..3071 (16B chunks)
    int sub = flat16 / 384, within = flat16 % 384;
    int p2 = g * 8 + sub;
    int b3 = p2 / 30, dl = p2 % 30;
    bf16x8 v = __builtin_nontemporal_load(
        (const bf16x8*)&hs1g[(size_t)(b3 * 60 + l0 + dl) * 3072 + within * 8]);
    int row = within / 24, col = (within % 24) * 8;
    *(bf16x8*)&a2[(sub * 16 + row) * 200 + col] = v;
  }
  __syncthreads();

  f32x4* xv = (f32x4*)xg2;
  for (int sub = 0; sub < 8; ++sub) {
    f32x4 acc[6];
    #pragma unroll
    for (int nt = 0; nt < 6; ++nt)
      acc[nt] = (f32x4){b2v[nt], b2v[nt], b2v[nt], b2v[nt]};
    #pragma unroll
    for (int kk = 0; kk < 6; ++kk) {
      const bf16x8 af = *(const bf16x8*)&a2[(sub * 16 + (lane & 15)) * 200 + kk * 32 + (lane >> 4) * 8];
      #pragma unroll
      for (int nt = 0; nt < 6; ++nt)
        acc[nt] = __builtin_amdgcn_mfma_f32_16x16x32_bf16(af, wb[kk][nt], acc[nt], 0, 0, 0);
    }
    int p2 = g * 8 + sub;
    #pragma unroll
    for (int nt = 0; nt < 6; ++nt)
      __builtin_nontemporal_store(acc[nt], &xv[(size_t)(((p2)*8 + wv) * 6 + nt) * 64 + lane]);
  }
}

// ================= K3: LSTM2 recurrence over [l0,l1), acc-init from xg2 ======
__global__ __launch_bounds__(512, 2) void k3_lstm2(
    const float* __restrict__ xsfc,
    const float* __restrict__ xmean_sca, const float* __restrict__ xdiv_sca,
    const float* __restrict__ Wtoa1, const float* __restrict__ btoa1,
    const float* __restrict__ Wtoa2, const float* __restrict__ btoa2,
    const unsigned short* __restrict__ pw,
    const float* __restrict__ xg2,
    unsigned short* __restrict__ hs2,
    float* __restrict__ cws,
    int l0, int l1, int initmode, int savec) {

  __shared__ float g_lds[16 * 772];
  __shared__ __align__(16) unsigned short a_lds[16 * 392];

  const int tid = threadIdx.x;
  const int lane = tid & 63;
  const int wv = tid >> 6;
  const int bid = blockIdx.x;
  const int r0 = bid * 16;

  int erow[6], ecol[6];
  #pragma unroll
  for (int e = 0; e < 6; ++e) { int idx = tid + 512 * e; erow[e] = idx / 192; ecol[e] = idx % 192; }

  float c[6];
  if (initmode == 0) {
    #pragma unroll
    for (int e = 0; e < 6; ++e) {
      int row = erow[e], col = ecol[e];
      float t0 = (xsfc[(r0 + row) * 24 + 0] - xmean_sca[0]) / xdiv_sca[0];
      float t1 = (xsfc[(r0 + row) * 24 + 1] - xmean_sca[1]) / xdiv_sca[1];
      float a1 = fmaf(t0, Wtoa1[col * 2], fmaf(t1, Wtoa1[col * 2 + 1], btoa1[col]));
      float a2 = fmaf(t0, Wtoa2[col * 2], fmaf(t1, Wtoa2[col * 2 + 1], btoa2[col]));
      a_lds[row * 392 + col] = f2bf(tanhf_(a1));
      c[e] = tanhf_(a2);
    }
  } else {
    #pragma unroll
    for (int e = 0; e < 6; ++e) {
      a_lds[erow[e] * 392 + ecol[e]] = hs2[(size_t)(bid * 60 + 29) * 3072 + tid + 512 * e];
      c[e] = cws[bid * 3072 + tid + 512 * e];
    }
  }

  bf16x8 w2[6][6];
  #pragma unroll
  for (int kk = 0; kk < 6; ++kk)
    #pragma unroll
    for (int nt = 0; nt < 6; ++nt)
      w2[kk][nt] = *(const bf16x8*)&pw[((SEG_B2H + kk * 48 + wv * 6 + nt) * 64 + lane) * 8];

  const f32x4* xv = (const f32x4*)xg2;
  f32x4 cur[6];
  #pragma unroll
  for (int nt = 0; nt < 6; ++nt)
    cur[nt] = __builtin_nontemporal_load(&xv[(size_t)((bid * 30 + 0) * 8 + wv) * 6 * 64 + nt * 64 + lane]);
  __syncthreads();

  for (int l = l0; l < l1; ++l) {
    f32x4 nxt[6];
    if (l + 1 < l1) {
      int p2n = bid * 30 + (l + 1 - l0);
      #pragma unroll
      for (int nt = 0; nt < 6; ++nt)
        nxt[nt] = __builtin_nontemporal_load(&xv[(size_t)(p2n * 8 + wv) * 6 * 64 + nt * 64 + lane]);
    }

    f32x4 acc[6];
    #pragma unroll
    for (int nt = 0; nt < 6; ++nt) acc[nt] = cur[nt];
    #pragma unroll
    for (int kk = 0; kk < 6; ++kk) {
      const bf16x8 af = *(const bf16x8*)&a_lds[(lane & 15) * 392 + kk * 32 + (lane >> 4) * 8];
      #pragma unroll
      for (int nt = 0; nt < 6; ++nt)
        acc[nt] = __builtin_amdgcn_mfma_f32_16x16x32_bf16(af, w2[kk][nt], acc[nt], 0, 0, 0);
    }
    #pragma unroll
    for (int nt = 0; nt < 6; ++nt)
      #pragma unroll
      for (int q = 0; q < 4; ++q)
        g_lds[((lane >> 4) * 4 + q) * 772 + wv * 96 + nt * 16 + (lane & 15)] = acc[nt][q];
    __syncthreads();

    #pragma unroll
    for (int e = 0; e < 6; ++e) {
      int row = erow[e], col = ecol[e];
      float gi = g_lds[row * 772 + col];
      float gf = g_lds[row * 772 + 192 + col];
      float gg = g_lds[row * 772 + 384 + col];
      float go = g_lds[row * 772 + 576 + col];
      c[e] = sigm(gf) * c[e] + sigm(gi) * tanhf_(gg);
      unsigned short hb = f2bf(sigm(go) * tanhf_(c[e]));
      a_lds[row * 392 + col] = hb;
      __builtin_nontemporal_store(hb, &hs2[(size_t)(bid * 60 + l) * 3072 + tid + 512 * e]);
    }
    #pragma unroll
    for (int nt = 0; nt < 6; ++nt) cur[nt] = nxt[nt];
    __syncthreads();
  }

  if (savec) {
    #pragma unroll
    for (int e = 0; e < 6; ++e)
      cws[bid * 3072 + tid + 512 * e] = c[e];
  }
}

// ================= K4: epilogue lat/out (blocks 0..959), outsfc (960..975) ===
__global__ __launch_bounds__(256, 4) void k4_out(
    const unsigned short* __restrict__ hs2,
    const float* __restrict__ Wlat, const float* __restrict__ blat,
    const float* __restrict__ Wout, const float* __restrict__ bout,
    const float* __restrict__ Wsfcout, const float* __restrict__ bsfcout,
    const float* __restrict__ yscale_lev, const float* __restrict__ yscale_sca,
    float* __restrict__ out, float* __restrict__ outsfc, float* __restrict__ latout) {

  __shared__ float wl[16 * 192];
  const int tid = threadIdx.x;
  const int bid = blockIdx.x;

  if (bid < 960) {
    for (int i = tid; i < 3072; i += 256) wl[i] = Wlat[i];
    __syncthreads();
    int R = bid * 256 + tid;               // 0..245759 == (b,l)
    int b = R / 60, l = R % 60, b3 = b >> 4, r = b & 15;
    const unsigned short* hp = hs2 + (size_t)(b3 * 60 + l) * 3072 + r * 192;
    float lat[16];
    #pragma unroll
    for (int cc = 0; cc < 16; ++cc) lat[cc] = blat[cc];
    for (int k8 = 0; k8 < 24; ++k8) {
      bf16x8 hv = __builtin_nontemporal_load((const bf16x8*)&hp[k8 * 8]);
      #pragma unroll
      for (int j = 0; j < 8; ++j) {
        float hf = bf2f((unsigned short)hv[j]);
        #pragma unroll
        for (int cc = 0; cc < 16; ++cc) lat[cc] = fmaf(hf, wl[cc * 192 + k8 * 8 + j], lat[cc]);
      }
    }
    #pragma unroll
    for (int cc = 0; cc < 16; ++cc)
      __builtin_nontemporal_store(lat[cc], &latout[(size_t)R * 16 + cc]);
    #pragma unroll
    for (int y = 0; y < 5; ++y) {
      float ov = bout[y];
      #pragma unroll
      for (int cc = 0; cc < 16; ++cc) ov = fmaf(lat[cc], Wout[y * 16 + cc], ov);
      __builtin_nontemporal_store(ov / yscale_lev[l * 5 + y], &out[(size_t)R * 5 + y]);
    }
  } else {
    for (int i = tid; i < 960; i += 256) wl[i] = Wsfcout[i];
    __syncthreads();
    int r = (bid - 960) * 256 + tid;       // 0..4095
    int b3 = r >> 4, rr = r & 15;
    const unsigned short* hp = hs2 + (size_t)(b3 * 60 + 59) * 3072 + rr * 192;
    float a5[5];
    #pragma unroll
    for (int y = 0; y < 5; ++y) a5[y] = bsfcout[y];
    for (int k8 = 0; k8 < 24; ++k8) {
      bf16x8 hv = __builtin_nontemporal_load((const bf16x8*)&hp[k8 * 8]);
      #pragma unroll
      for (int j = 0; j < 8; ++j) {
        float hf = bf2f((unsigned short)hv[j]);
        #pragma unroll
        for (int y = 0; y < 5; ++y) a5[y] = fmaf(hf, wl[y * 192 + k8 * 8 + j], a5[y]);
      }
    }
    #pragma unroll
    for (int y = 0; y < 5; ++y)
      outsfc[(size_t)r * 5 + y] = a5[y] / yscale_sca[y];
  }
}

// ================= Fallback: R2 monolithic kernel (verified) =================
__global__ __launch_bounds__(512, 2) void lstm_main(
    const float* __restrict__ xlev, const float* __restrict__ xsfc,
    const float* __restrict__ hmem,
    const float* __restrict__ xmean_lev, const float* __restrict__ xdiv_lev,
    const float* __restrict__ xmean_sca, const float* __restrict__ xdiv_sca,
    const float* __restrict__ yscale_lev, const float* __restrict__ yscale_sca,
    const float* __restrict__ b2,
    const float* __restrict__ Wsfc1, const float* __restrict__ bsfc1,
    const float* __restrict__ Wsfc2, const float* __restrict__ bsfc2,
    const float* __restrict__ Wtoa1, const float* __restrict__ btoa1,
    const float* __restrict__ Wtoa2, const float* __restrict__ btoa2,
    const float* __restrict__ Wlat, const float* __restrict__ blat,
    const float* __restrict__ Wout, const float* __restrict__ bout,
    const float* __restrict__ Wsfcout, const float* __restrict__ bsfcout,
    const unsigned short* __restrict__ pw,
    unsigned short* __restrict__ hs1g,
    float* __restrict__ out, float* __restrict__ outsfc, float* __restrict__ latout) {

  __shared__ float g_lds[16 * 772];
  __shared__ __align__(16) unsigned short a_lds[16 * 392];
  __shared__ float misc[16 * 24];
  __shared__ float toa_lds[32];

  const int tid = threadIdx.x;
  const int lane = tid & 63;
  const int wv = tid >> 6;
  const int bid = blockIdx.x;
  const int r0 = bid * 16;

  int erow[6], ecol[6];
  #pragma unroll
  for (int e = 0; e < 6; ++e) { int idx = tid + 512 * e; erow[e] = idx / 192; ecol[e] = idx % 192; }

  if (tid < 384) {
    int r = tid / 24, j = tid % 24;
    misc[tid] = (xsfc[(r0 + r) * 24 + j] - xmean_sca[j]) / xdiv_sca[j];
  }
  __syncthreads();
  if (tid < 32) toa_lds[tid] = misc[(tid >> 1) * 24 + (tid & 1)];

  float c[6];
  #pragma unroll
  for (int e = 0; e < 6; ++e) {
    int row = erow[e], col = ecol[e];
    float a1 = bsfc1[col], a2 = bsfc2[col];
    for (int k = 0; k < 24; ++k) {
      float s = misc[row * 24 + k];
      a1 = fmaf(s, Wsfc1[col * 24 + k], a1);
      a2 = fmaf(s, Wsfc2[col * 24 + k], a2);
    }
    a_lds[row * 392 + col] = f2bf(tanhf_(a1));
    c[e] = tanhf_(a2);
  }

  bf16x8 w1[7][6];
  #pragma unroll
  for (int kk = 0; kk < 7; ++kk)
    #pragma unroll
    for (int nt = 0; nt < 6; ++nt)
      w1[kk][nt] = *(const bf16x8*)&pw[((kk * 48 + wv * 6 + nt) * 64 + lane) * 8];

  const int xr = tid >> 5, xj = tid & 31;
  float xraw = 0.f;
  if (xj < 15)      xraw = __builtin_nontemporal_load(&xlev[((r0 + xr) * 60 + 59) * 15 + xj]);
  else if (xj < 31) xraw = __builtin_nontemporal_load(&hmem[((r0 + xr) * 60 + 59) * 16 + (xj - 15)]);

  for (int l = 59; l >= 0; --l) {
    {
      float v;
      if (xj < 15)      v = (xraw - xmean_lev[l * 15 + xj]) / xdiv_lev[l * 15 + xj];
      else if (xj < 31) v = xraw;
      else              v = 1.0f;
      a_lds[xr * 392 + 192 + xj] = f2bf(v);
    }
    if (l > 0) {
      if (xj < 15)      xraw = __builtin_nontemporal_load(&xlev[((r0 + xr) * 60 + l - 1) * 15 + xj]);
      else if (xj < 31) xraw = __builtin_nontemporal_load(&hmem[((r0 + xr) * 60 + l - 1) * 16 + (xj - 15)]);
    }
    __syncthreads();

    f32x4 acc[6];
    #pragma unroll
    for (int nt = 0; nt < 6; ++nt) acc[nt] = (f32x4){0.f, 0.f, 0.f, 0.f};
    #pragma unroll
    for (int kk = 0; kk < 7; ++kk) {
      const bf16x8 af = *(const bf16x8*)&a_lds[(lane & 15) * 392 + kk * 32 + (lane >> 4) * 8];
      #pragma unroll
      for (int nt = 0; nt < 6; ++nt)
        acc[nt] = __builtin_amdgcn_mfma_f32_16x16x32_bf16(af, w1[kk][nt], acc[nt], 0, 0, 0);
    }
    #pragma unroll
    for (int nt = 0; nt < 6; ++nt)
      #pragma unroll
      for (int q = 0; q < 4; ++q)
        g_lds[((lane >> 4) * 4 + q) * 772 + wv * 96 + nt * 16 + (lane & 15)] = acc[nt][q];
    __syncthreads();

    #pragma unroll
    for (int e = 0; e < 6; ++e) {
      int row = erow[e], col = ecol[e];
      float gi = g_lds[row * 772 + col];
      float gf = g_lds[row * 772 + 192 + col];
      float gg = g_lds[row * 772 + 384 + col];
      float go = g_lds[row * 772 + 576 + col];
      c[e] = sigm(gf) * c[e] + sigm(gi) * tanhf_(gg);
      float hv = sigm(go) * tanhf_(c[e]);
      unsigned short hb = f2bf(hv);
      a_lds[row * 392 + col] = hb;
      __builtin_nontemporal_store(hb, &hs1g[(bid * 60 + l) * 3072 + tid + 512 * e]);
    }
  }

  #pragma unroll
  for (int e = 0; e < 6; ++e) {
    int row = erow[e], col = ecol[e];
    float t0 = toa_lds[row * 2], t1 = toa_lds[row * 2 + 1];
    float a1 = fmaf(t0, Wtoa1[col * 2], fmaf(t1, Wtoa1[col * 2 + 1], btoa1[col]));
    float a2 = fmaf(t0, Wtoa2[col * 2], fmaf(t1, Wtoa2[col * 2 + 1], btoa2[col]));
    a_lds[row * 392 + col] = f2bf(tanhf_(a1));
    c[e] = tanhf_(a2);
  }
  bf16x8 w2[6][6];
  #pragma unroll
  for (int kk = 0; kk < 6; ++kk)
    #pragma unroll
    for (int nt = 0; nt < 6; ++nt)
      w2[kk][nt] = *(const bf16x8*)&pw[((SEG_B2H + kk * 48 + wv * 6 + nt) * 64 + lane) * 8];

  const bf16x8* hs1v = (const bf16x8*)hs1g;
  bf16x8 hv8;
  if (tid < 384) hv8 = __builtin_nontemporal_load(&hs1v[(bid * 60 + 0) * 384 + tid]);

  for (int l = 0; l < 60; ++l) {
    if (tid < 384)
      *(bf16x8*)&a_lds[(tid / 24) * 392 + 192 + (tid % 24) * 8] = hv8;
    if (tid < 384 && l < 59)
      hv8 = __builtin_nontemporal_load(&hs1v[(bid * 60 + l + 1) * 384 + tid]);

    bf16x8 wx0[6], wx1[6];
    #pragma unroll
    for (int nt = 0; nt < 6; ++nt)
      wx0[nt] = *(const bf16x8*)&pw[((SEG_B2X + 0 * 48 + wv * 6 + nt) * 64 + lane) * 8];
    #pragma unroll
    for (int nt = 0; nt < 6; ++nt)
      wx1[nt] = *(const bf16x8*)&pw[((SEG_B2X + 1 * 48 + wv * 6 + nt) * 64 + lane) * 8];

    __syncthreads();

    f32x4 acc[6];
    #pragma unroll
    for (int nt = 0; nt < 6; ++nt) acc[nt] = (f32x4){0.f, 0.f, 0.f, 0.f};

    #pragma unroll
    for (int g = 0; g < 6; ++g) {
      const bf16x8 ah = *(const bf16x8*)&a_lds[(lane & 15) * 392 + g * 32 + (lane >> 4) * 8];
      #pragma unroll
      for (int nt = 0; nt < 6; ++nt)
        acc[nt] = __builtin_amdgcn_mfma_f32_16x16x32_bf16(ah, w2[g][nt], acc[nt], 0, 0, 0);
      const bf16x8 ax = *(const bf16x8*)&a_lds[(lane & 15) * 392 + 192 + g * 32 + (lane >> 4) * 8];
      #pragma unroll
      for (int nt = 0; nt < 6; ++nt)
        acc[nt] = __builtin_amdgcn_mfma_f32_16x16x32_bf16(ax, (g & 1) ? wx1[nt] : wx0[nt], acc[nt], 0, 0, 0);
      if (g < 4) {
        #pragma unroll
        for (int nt = 0; nt < 6; ++nt) {
          bf16x8 nw = *(const bf16x8*)&pw[((SEG_B2X + (g + 2) * 48 + wv * 6 + nt) * 64 + lane) * 8];
          if (g & 1) wx1[nt] = nw; else wx0[nt] = nw;
        }
      }
    }
    #pragma unroll
    for (int nt = 0; nt < 6; ++nt)
      #pragma unroll
      for (int q = 0; q < 4; ++q)
        g_lds[((lane >> 4) * 4 + q) * 772 + wv * 96 + nt * 16 + (lane & 15)] = acc[nt][q];
    __syncthreads();

    #pragma unroll
    for (int e = 0; e < 6; ++e) {
      int row = erow[e], col = ecol[e];
      float gi = g_lds[row * 772 + col]       + b2[col];
      float gf = g_lds[row * 772 + 192 + col] + b2[192 + col];
      float gg = g_lds[row * 772 + 384 + col] + b2[384 + col];
      float go = g_lds[row * 772 + 576 + col] + b2[576 + col];
      c[e] = sigm(gf) * c[e] + sigm(gi) * tanhf_(gg);
      a_lds[row * 392 + col] = f2bf(sigm(go) * tanhf_(c[e]));
    }
    __syncthreads();

    if (tid < 256) {
      int r = tid >> 4, cc = tid & 15;
      float lv = blat[cc];
      for (int k = 0; k < 192; k += 8) {
        #pragma unroll
        for (int jj = 0; jj < 8; ++jj)
          lv = fmaf(bf2f(a_lds[r * 392 + k + jj]), Wlat[cc * 192 + k + jj], lv);
      }
      __builtin_nontemporal_store(lv, &latout[((r0 + r) * 60 + l) * 16 + cc]);
      misc[r * 16 + cc] = lv;
    }
    __syncthreads();
    if (tid < 80) {
      int r = tid / 5, y = tid % 5;
      float ov = bout[y];
      #pragma unroll
      for (int k = 0; k < 16; ++k) ov = fmaf(misc[r * 16 + k], Wout[y * 16 + k], ov);
      __builtin_nontemporal_store(ov / yscale_lev[l * 5 + y], &out[((r0 + r) * 60 + l) * 5 + y]);
    }
  }

  if (tid < 80) {
    int r = tid / 5, y = tid % 5;
    float ov = bsfcout[y];
    for (int k = 0; k < 192; ++k)
      ov = fmaf(bf2f(a_lds[r * 392 + k]), Wsfcout[y * 192 + k], ov);
    outsfc[(r0 + r) * 5 + y] = ov / yscale_sca[y];
  }
}

extern "C" void kernel_launch(void* const* d_in, const int* in_sizes, int n_in,
                              void* d_out, int out_size, void* d_ws, size_t ws_size,
                              hipStream_t stream) {
  (void)in_sizes; (void)n_in; (void)out_size;

  const float* xlev      = (const float*)d_in[0];
  const float* xsfc      = (const float*)d_in[1];
  const float* hmem      = (const float*)d_in[2];
  const float* xmean_lev = (const float*)d_in[3];
  const float* xdiv_lev  = (const float*)d_in[4];
  const float* xmean_sca = (const float*)d_in[5];
  const float* xdiv_sca  = (const float*)d_in[6];
  const float* yscale_lev= (const float*)d_in[7];
  const float* yscale_sca= (const float*)d_in[8];
  const float* Wih1      = (const float*)d_in[9];
  const float* Whh1      = (const float*)d_in[10];
  const float* b1        = (const float*)d_in[11];
  const float* Wih2      = (const float*)d_in[12];
  const float* Whh2      = (const float*)d_in[13];
  const float* b2        = (const float*)d_in[14];
  const float* Wsfc1     = (const float*)d_in[15];
  const float* bsfc1     = (const float*)d_in[16];
  const float* Wsfc2     = (const float*)d_in[17];
  const float* bsfc2     = (const float*)d_in[18];
  const float* Wtoa1     = (const float*)d_in[19];
  const float* btoa1     = (const float*)d_in[20];
  const float* Wtoa2     = (const float*)d_in[21];
  const float* btoa2     = (const float*)d_in[22];
  const float* Wlat      = (const float*)d_in[23];
  const float* blat      = (const float*)d_in[24];
  const float* Wout      = (const float*)d_in[25];
  const float* bout      = (const float*)d_in[26];
  const float* Wsfcout   = (const float*)d_in[27];
  const float* bsfcout   = (const float*)d_in[28];

  unsigned short* pw   = (unsigned short*)d_ws;
  unsigned short* hsg  = (unsigned short*)((char*)d_ws + HS1_OFF);   // hs1, then hs2
  float* xg2           = (float*)((char*)d_ws + XG2_OFF);
  float* cws           = (float*)((char*)d_ws + CWS_OFF);
  float* out    = (float*)d_out;
  float* outsfc = out + (size_t)4096 * 60 * 5;
  float* latout = outsfc + (size_t)4096 * 5;

  hipLaunchKernelGGL(pack_kernel, dim3(PACK_TOTAL / 256), dim3(256), 0, stream,
                     Wih1, Whh1, b1, Wih2, Whh2, pw);

  if (ws_size >= (size_t)NEED_FULL) {
    hipLaunchKernelGGL(k1_lstm1, dim3(256), dim3(512), 0, stream,
                       xlev, xsfc, hmem, xmean_lev, xdiv_lev, xmean_sca, xdiv_sca,
                       Wsfc1, bsfc1, Wsfc2, bsfc2, pw, hsg);
    hipLaunchKernelGGL(k2_xg2, dim3(960), dim3(512), 0, stream, pw, hsg, b2, xg2, 0);
    hipLaunchKernelGGL(k3_lstm2, dim3(256), dim3(512), 0, stream,
                       xsfc, xmean_sca, xdiv_sca, Wtoa1, btoa1, Wtoa2, btoa2,
                       pw, xg2, hsg, cws, 0, 30, 0, 1);
    hipLaunchKernelGGL(k2_xg2, dim3(960), dim3(512), 0, stream, pw, hsg, b2, xg2, 30);
    hipLaunchKernelGGL(k3_lstm2, dim3(256), dim3(512), 0, stream,
                       xsfc, xmean_sca, xdiv_sca, Wtoa1, btoa1, Wtoa2, btoa2,
                       pw, xg2, hsg, cws, 30, 60, 1, 0);
    hipLaunchKernelGGL(k4_out, dim3(976), dim3(256), 0, stream,
                       hsg, Wlat, blat, Wout, bout, Wsfcout, bsfcout,
                       yscale_lev, yscale_sca, out, outsfc, latout);
  } else if (ws_size >= (size_t)NEED_MIN) {
    hipLaunchKernelGGL(lstm_main, dim3(256), dim3(512), 0, stream,
                       xlev, xsfc, hmem, xmean_lev, xdiv_lev, xmean_sca, xdiv_sca,
                       yscale_lev, yscale_sca, b2,
                       Wsfc1, bsfc1, Wsfc2, bsfc2, Wtoa1, btoa1, Wtoa2, btoa2,
                       Wlat, blat, Wout, bout, Wsfcout, bsfcout,
                       pw, hsg, out, outsfc, latout);
  }
}

// Round 6
// 777.778 us; speedup vs baseline: 1.8965x; 1.8965x over previous
//
#include <hip/hip_runtime.h>
#include <hip/hip_bf16.h>

// LSTM_autoreg for MI355X.  R6: workspace-ADAPTIVE kernel split.
// R5 finding: ws_size < 459 MiB -> R3 split never ran (fallback reproduced the
// 1470us Wih2-BW wall). This version chunks the level range so the xg2 buffer
// fits whatever ws_size offers: C = (ws - 98.6MB)/12.58MB levels per chunk,
// ceil(60/C) K2->K3 pairs. Also dropped nontemporal hints on intermediates:
// R1->R2 evidence showed NT stores bypass the LLC and ADD HBM traffic
// (FETCH 1.94->2.16 GB, WRITE 185->316 MB).

#define DEV static __device__ __forceinline__

typedef __attribute__((ext_vector_type(8))) short bf16x8;
typedef __attribute__((ext_vector_type(4))) float f32x4;

DEV unsigned short f2bf(float f) {
  unsigned int u = __builtin_bit_cast(unsigned int, f);
  unsigned int r = (u + 0x7fffu + ((u >> 16) & 1u)) >> 16;
  return (unsigned short)r;
}
DEV float bf2f(unsigned short s) {
  return __builtin_bit_cast(float, ((unsigned int)s) << 16);
}
DEV float sigm(float x) {
  float e = __builtin_amdgcn_exp2f(-1.44269504089f * x);
  return __builtin_amdgcn_rcpf(1.0f + e);
}
DEV float tanhf_(float x) {
  float e = __builtin_amdgcn_exp2f(2.88539008178f * x);
  return 1.0f - 2.0f * __builtin_amdgcn_rcpf(1.0f + e);
}

// ---- packed fragment layout in d_ws (ushort/bf16) ----
#define SEG_B2H 336
#define SEG_B2X 624
#define PACK_TOTAL (912 * 512)

// ---- workspace layout (bytes) ----
#define HS1_OFF   1048576u                   // pw in [0, 933888)
#define HS1_BYTES 94371840u                  // hs1 -> hs2 (aliased), bf16
#define CWS_OFF   95420416u                  // c-state checkpoint (3 MB)
#define CWS_BYTES 3145728u
#define XG2_OFF   98566144u                  // xg2 chunk, fp32 frag layout
#define XG2_PER_LEVEL 12582912u              // 4096*768*4
#define NEED_MIN  (HS1_OFF + HS1_BYTES)

__global__ void pack_kernel(const float* __restrict__ Wih1,
                            const float* __restrict__ Whh1,
                            const float* __restrict__ b1,
                            const float* __restrict__ Wih2,
                            const float* __restrict__ Whh2,
                            unsigned short* __restrict__ pw) {
  int idx = blockIdx.x * 256 + threadIdx.x;          // 0..466943
  int j = idx & 7;
  int lane = (idx >> 3) & 63;
  int rest = idx >> 9;
  int n, k; float v;
  if (rest < SEG_B2H) {
    int kk = rest / 48, nt = rest % 48;
    n = nt * 16 + (lane & 15);
    k = kk * 32 + (lane >> 4) * 8 + j;               // 0..223
    if (k < 192) v = Whh1[n * 192 + k];
    else { int t = k - 192; v = (t < 31) ? Wih1[n * 31 + t] : b1[n]; }
  } else if (rest < SEG_B2X) {
    int r2 = rest - SEG_B2H; int kk = r2 / 48, nt = r2 % 48;
    n = nt * 16 + (lane & 15);
    k = kk * 32 + (lane >> 4) * 8 + j;
    v = Whh2[n * 192 + k];
  } else {
    int r2 = rest - SEG_B2X; int kk = r2 / 48, nt = r2 % 48;
    n = nt * 16 + (lane & 15);
    k = kk * 32 + (lane >> 4) * 8 + j;
    v = Wih2[n * 192 + k];
  }
  pw[idx] = f2bf(v);
}

// ================= K1: LSTM1 recurrence (levels 59->0), store hs1 ============
__global__ __launch_bounds__(512, 2) void k1_lstm1(
    const float* __restrict__ xlev, const float* __restrict__ xsfc,
    const float* __restrict__ hmem,
    const float* __restrict__ xmean_lev, const float* __restrict__ xdiv_lev,
    const float* __restrict__ xmean_sca, const float* __restrict__ xdiv_sca,
    const float* __restrict__ Wsfc1, const float* __restrict__ bsfc1,
    const float* __restrict__ Wsfc2, const float* __restrict__ bsfc2,
    const unsigned short* __restrict__ pw,
    unsigned short* __restrict__ hs1g) {

  __shared__ float g_lds[16 * 772];
  __shared__ __align__(16) unsigned short a_lds[16 * 392];
  __shared__ float misc[16 * 24];

  const int tid = threadIdx.x;
  const int lane = tid & 63;
  const int wv = tid >> 6;
  const int bid = blockIdx.x;
  const int r0 = bid * 16;

  int erow[6], ecol[6];
  #pragma unroll
  for (int e = 0; e < 6; ++e) { int idx = tid + 512 * e; erow[e] = idx / 192; ecol[e] = idx % 192; }

  if (tid < 384) {
    int r = tid / 24, j = tid % 24;
    misc[tid] = (xsfc[(r0 + r) * 24 + j] - xmean_sca[j]) / xdiv_sca[j];
  }
  __syncthreads();

  float c[6];
  #pragma unroll
  for (int e = 0; e < 6; ++e) {
    int row = erow[e], col = ecol[e];
    float a1 = bsfc1[col], a2 = bsfc2[col];
    for (int k = 0; k < 24; ++k) {
      float s = misc[row * 24 + k];
      a1 = fmaf(s, Wsfc1[col * 24 + k], a1);
      a2 = fmaf(s, Wsfc2[col * 24 + k], a2);
    }
    a_lds[row * 392 + col] = f2bf(tanhf_(a1));
    c[e] = tanhf_(a2);
  }

  bf16x8 w1[7][6];
  #pragma unroll
  for (int kk = 0; kk < 7; ++kk)
    #pragma unroll
    for (int nt = 0; nt < 6; ++nt)
      w1[kk][nt] = *(const bf16x8*)&pw[((kk * 48 + wv * 6 + nt) * 64 + lane) * 8];

  const int xr = tid >> 5, xj = tid & 31;
  float xraw = 0.f;
  if (xj < 15)      xraw = __builtin_nontemporal_load(&xlev[((r0 + xr) * 60 + 59) * 15 + xj]);
  else if (xj < 31) xraw = __builtin_nontemporal_load(&hmem[((r0 + xr) * 60 + 59) * 16 + (xj - 15)]);

  for (int l = 59; l >= 0; --l) {
    {
      float v;
      if (xj < 15)      v = (xraw - xmean_lev[l * 15 + xj]) / xdiv_lev[l * 15 + xj];
      else if (xj < 31) v = xraw;
      else              v = 1.0f;
      a_lds[xr * 392 + 192 + xj] = f2bf(v);
    }
    if (l > 0) {
      if (xj < 15)      xraw = __builtin_nontemporal_load(&xlev[((r0 + xr) * 60 + l - 1) * 15 + xj]);
      else if (xj < 31) xraw = __builtin_nontemporal_load(&hmem[((r0 + xr) * 60 + l - 1) * 16 + (xj - 15)]);
    }
    __syncthreads();

    f32x4 acc[6];
    #pragma unroll
    for (int nt = 0; nt < 6; ++nt) acc[nt] = (f32x4){0.f, 0.f, 0.f, 0.f};
    #pragma unroll
    for (int kk = 0; kk < 7; ++kk) {
      const bf16x8 af = *(const bf16x8*)&a_lds[(lane & 15) * 392 + kk * 32 + (lane >> 4) * 8];
      #pragma unroll
      for (int nt = 0; nt < 6; ++nt)
        acc[nt] = __builtin_amdgcn_mfma_f32_16x16x32_bf16(af, w1[kk][nt], acc[nt], 0, 0, 0);
    }
    #pragma unroll
    for (int nt = 0; nt < 6; ++nt)
      #pragma unroll
      for (int q = 0; q < 4; ++q)
        g_lds[((lane >> 4) * 4 + q) * 772 + wv * 96 + nt * 16 + (lane & 15)] = acc[nt][q];
    __syncthreads();

    #pragma unroll
    for (int e = 0; e < 6; ++e) {
      int row = erow[e], col = ecol[e];
      float gi = g_lds[row * 772 + col];
      float gf = g_lds[row * 772 + 192 + col];
      float gg = g_lds[row * 772 + 384 + col];
      float go = g_lds[row * 772 + 576 + col];
      c[e] = sigm(gf) * c[e] + sigm(gi) * tanhf_(gg);
      float hv = sigm(go) * tanhf_(c[e]);
      unsigned short hb = f2bf(hv);
      a_lds[row * 392 + col] = hb;
      hs1g[(size_t)(bid * 60 + l) * 3072 + tid + 512 * e] = hb;   // cacheable: LLC holds hs1
    }
  }
}

// ================= K2: xg2 = hs1 @ Wih2.T + b2, fp32 fragment layout =========
// chunk of Cc levels starting at l0. grid = 32*Cc blocks; block g covers tiles
// p2 = 8g..8g+7 ; p2 = b3*Cc + dl.
__global__ __launch_bounds__(512, 2) void k2_xg2(
    const unsigned short* __restrict__ pw,
    const unsigned short* __restrict__ hs1g,
    const float* __restrict__ b2,
    float* __restrict__ xg2, int l0, int Cc) {

  __shared__ __align__(16) unsigned short a2[8 * 16 * 200];   // padded stride 200

  const int tid = threadIdx.x;
  const int lane = tid & 63;
  const int wv = tid >> 6;
  const int g = blockIdx.x;

  bf16x8 wb[6][6];
  #pragma unroll
  for (int kk = 0; kk < 6; ++kk)
    #pragma unroll
    for (int nt = 0; nt < 6; ++nt)
      wb[kk][nt] = *(const bf16x8*)&pw[((SEG_B2X + kk * 48 + wv * 6 + nt) * 64 + lane) * 8];

  float b2v[6];
  #pragma unroll
  for (int nt = 0; nt < 6; ++nt) b2v[nt] = b2[wv * 96 + nt * 16 + (lane & 15)];

  // stage 8 hs1 tiles -> LDS (50 KB, 6x16B per thread)
  #pragma unroll
  for (int i = 0; i < 6; ++i) {
    int flat16 = tid + 512 * i;            // 0..3071 (16B chunks)
    int sub = flat16 / 384, within = flat16 % 384;
    int p2 = g * 8 + sub;
    int b3 = p2 / Cc, dl = p2 % Cc;
    bf16x8 v = *(const bf16x8*)&hs1g[(size_t)(b3 * 60 + l0 + dl) * 3072 + within * 8];
    int row = within / 24, col = (within % 24) * 8;
    *(bf16x8*)&a2[(sub * 16 + row) * 200 + col] = v;
  }
  __syncthreads();

  f32x4* xv = (f32x4*)xg2;
  for (int sub = 0; sub < 8; ++sub) {
    f32x4 acc[6];
    #pragma unroll
    for (int nt = 0; nt < 6; ++nt)
      acc[nt] = (f32x4){b2v[nt], b2v[nt], b2v[nt], b2v[nt]};
    #pragma unroll
    for (int kk = 0; kk < 6; ++kk) {
      const bf16x8 af = *(const bf16x8*)&a2[(sub * 16 + (lane & 15)) * 200 + kk * 32 + (lane >> 4) * 8];
      #pragma unroll
      for (int nt = 0; nt < 6; ++nt)
        acc[nt] = __builtin_amdgcn_mfma_f32_16x16x32_bf16(af, wb[kk][nt], acc[nt], 0, 0, 0);
    }
    int p2 = g * 8 + sub;
    #pragma unroll
    for (int nt = 0; nt < 6; ++nt)
      xv[(size_t)((p2 * 8 + wv) * 6 + nt) * 64 + lane] = acc[nt];
  }
}

// ================= K3: LSTM2 recurrence over [l0,l1), acc-init from xg2 ======
__global__ __launch_bounds__(512, 2) void k3_lstm2(
    const float* __restrict__ xsfc,
    const float* __restrict__ xmean_sca, const float* __restrict__ xdiv_sca,
    const float* __restrict__ Wtoa1, const float* __restrict__ btoa1,
    const float* __restrict__ Wtoa2, const float* __restrict__ btoa2,
    const unsigned short* __restrict__ pw,
    const float* __restrict__ xg2,
    unsigned short* __restrict__ hs2,
    float* __restrict__ cws,
    int l0, int l1, int savec) {

  __shared__ float g_lds[16 * 772];
  __shared__ __align__(16) unsigned short a_lds[16 * 392];

  const int tid = threadIdx.x;
  const int lane = tid & 63;
  const int wv = tid >> 6;
  const int bid = blockIdx.x;
  const int r0 = bid * 16;
  const int Cc = l1 - l0;

  int erow[6], ecol[6];
  #pragma unroll
  for (int e = 0; e < 6; ++e) { int idx = tid + 512 * e; erow[e] = idx / 192; ecol[e] = idx % 192; }

  float c[6];
  if (l0 == 0) {
    #pragma unroll
    for (int e = 0; e < 6; ++e) {
      int row = erow[e], col = ecol[e];
      float t0 = (xsfc[(r0 + row) * 24 + 0] - xmean_sca[0]) / xdiv_sca[0];
      float t1 = (xsfc[(r0 + row) * 24 + 1] - xmean_sca[1]) / xdiv_sca[1];
      float a1 = fmaf(t0, Wtoa1[col * 2], fmaf(t1, Wtoa1[col * 2 + 1], btoa1[col]));
      float a2 = fmaf(t0, Wtoa2[col * 2], fmaf(t1, Wtoa2[col * 2 + 1], btoa2[col]));
      a_lds[row * 392 + col] = f2bf(tanhf_(a1));
      c[e] = tanhf_(a2);
    }
  } else {
    #pragma unroll
    for (int e = 0; e < 6; ++e) {
      a_lds[erow[e] * 392 + ecol[e]] = hs2[(size_t)(bid * 60 + (l0 - 1)) * 3072 + tid + 512 * e];
      c[e] = cws[bid * 3072 + tid + 512 * e];
    }
  }

  bf16x8 w2[6][6];
  #pragma unroll
  for (int kk = 0; kk < 6; ++kk)
    #pragma unroll
    for (int nt = 0; nt < 6; ++nt)
      w2[kk][nt] = *(const bf16x8*)&pw[((SEG_B2H + kk * 48 + wv * 6 + nt) * 64 + lane) * 8];

  const f32x4* xv = (const f32x4*)xg2;
  f32x4 cur[6];
  #pragma unroll
  for (int nt = 0; nt < 6; ++nt)
    cur[nt] = xv[(size_t)((bid * Cc + 0) * 8 + wv) * 6 * 64 + nt * 64 + lane];
  __syncthreads();

  for (int l = l0; l < l1; ++l) {
    f32x4 nxt[6];
    if (l + 1 < l1) {
      int p2n = bid * Cc + (l + 1 - l0);
      #pragma unroll
      for (int nt = 0; nt < 6; ++nt)
        nxt[nt] = xv[(size_t)(p2n * 8 + wv) * 6 * 64 + nt * 64 + lane];
    }

    f32x4 acc[6];
    #pragma unroll
    for (int nt = 0; nt < 6; ++nt) acc[nt] = cur[nt];
    #pragma unroll
    for (int kk = 0; kk < 6; ++kk) {
      const bf16x8 af = *(const bf16x8*)&a_lds[(lane & 15) * 392 + kk * 32 + (lane >> 4) * 8];
      #pragma unroll
      for (int nt = 0; nt < 6; ++nt)
        acc[nt] = __builtin_amdgcn_mfma_f32_16x16x32_bf16(af, w2[kk][nt], acc[nt], 0, 0, 0);
    }
    #pragma unroll
    for (int nt = 0; nt < 6; ++nt)
      #pragma unroll
      for (int q = 0; q < 4; ++q)
        g_lds[((lane >> 4) * 4 + q) * 772 + wv * 96 + nt * 16 + (lane & 15)] = acc[nt][q];
    __syncthreads();

    #pragma unroll
    for (int e = 0; e < 6; ++e) {
      int row = erow[e], col = ecol[e];
      float gi = g_lds[row * 772 + col];
      float gf = g_lds[row * 772 + 192 + col];
      float gg = g_lds[row * 772 + 384 + col];
      float go = g_lds[row * 772 + 576 + col];
      c[e] = sigm(gf) * c[e] + sigm(gi) * tanhf_(gg);
      unsigned short hb = f2bf(sigm(go) * tanhf_(c[e]));
      a_lds[row * 392 + col] = hb;
      hs2[(size_t)(bid * 60 + l) * 3072 + tid + 512 * e] = hb;
    }
    if (l + 1 < l1) {
      #pragma unroll
      for (int nt = 0; nt < 6; ++nt) cur[nt] = nxt[nt];
    }
    __syncthreads();
  }

  if (savec) {
    #pragma unroll
    for (int e = 0; e < 6; ++e)
      cws[bid * 3072 + tid + 512 * e] = c[e];
  }
}

// ================= K4: epilogue lat/out (blocks 0..959), outsfc (960..975) ===
__global__ __launch_bounds__(256, 4) void k4_out(
    const unsigned short* __restrict__ hs2,
    const float* __restrict__ Wlat, const float* __restrict__ blat,
    const float* __restrict__ Wout, const float* __restrict__ bout,
    const float* __restrict__ Wsfcout, const float* __restrict__ bsfcout,
    const float* __restrict__ yscale_lev, const float* __restrict__ yscale_sca,
    float* __restrict__ out, float* __restrict__ outsfc, float* __restrict__ latout) {

  __shared__ float wl[16 * 192];
  const int tid = threadIdx.x;
  const int bid = blockIdx.x;

  if (bid < 960) {
    for (int i = tid; i < 3072; i += 256) wl[i] = Wlat[i];
    __syncthreads();
    int R = bid * 256 + tid;               // 0..245759 == (b,l)
    int b = R / 60, l = R % 60, b3 = b >> 4, r = b & 15;
    const unsigned short* hp = hs2 + (size_t)(b3 * 60 + l) * 3072 + r * 192;
    float lat[16];
    #pragma unroll
    for (int cc = 0; cc < 16; ++cc) lat[cc] = blat[cc];
    for (int k8 = 0; k8 < 24; ++k8) {
      bf16x8 hv = *(const bf16x8*)&hp[k8 * 8];
      #pragma unroll
      for (int j = 0; j < 8; ++j) {
        float hf = bf2f((unsigned short)hv[j]);
        #pragma unroll
        for (int cc = 0; cc < 16; ++cc) lat[cc] = fmaf(hf, wl[cc * 192 + k8 * 8 + j], lat[cc]);
      }
    }
    #pragma unroll
    for (int cc = 0; cc < 16; ++cc)
      latout[(size_t)R * 16 + cc] = lat[cc];
    #pragma unroll
    for (int y = 0; y < 5; ++y) {
      float ov = bout[y];
      #pragma unroll
      for (int cc = 0; cc < 16; ++cc) ov = fmaf(lat[cc], Wout[y * 16 + cc], ov);
      out[(size_t)R * 5 + y] = ov / yscale_lev[l * 5 + y];
    }
  } else {
    for (int i = tid; i < 960; i += 256) wl[i] = Wsfcout[i];
    __syncthreads();
    int r = (bid - 960) * 256 + tid;       // 0..4095
    int b3 = r >> 4, rr = r & 15;
    const unsigned short* hp = hs2 + (size_t)(b3 * 60 + 59) * 3072 + rr * 192;
    float a5[5];
    #pragma unroll
    for (int y = 0; y < 5; ++y) a5[y] = bsfcout[y];
    for (int k8 = 0; k8 < 24; ++k8) {
      bf16x8 hv = *(const bf16x8*)&hp[k8 * 8];
      #pragma unroll
      for (int j = 0; j < 8; ++j) {
        float hf = bf2f((unsigned short)hv[j]);
        #pragma unroll
        for (int y = 0; y < 5; ++y) a5[y] = fmaf(hf, wl[y * 192 + k8 * 8 + j], a5[y]);
      }
    }
    #pragma unroll
    for (int y = 0; y < 5; ++y)
      outsfc[(size_t)r * 5 + y] = a5[y] / yscale_sca[y];
  }
}

// ================= Fallback: R2 monolithic kernel (verified) =================
__global__ __launch_bounds__(512, 2) void lstm_main(
    const float* __restrict__ xlev, const float* __restrict__ xsfc,
    const float* __restrict__ hmem,
    const float* __restrict__ xmean_lev, const float* __restrict__ xdiv_lev,
    const float* __restrict__ xmean_sca, const float* __restrict__ xdiv_sca,
    const float* __restrict__ yscale_lev, const float* __restrict__ yscale_sca,
    const float* __restrict__ b2,
    const float* __restrict__ Wsfc1, const float* __restrict__ bsfc1,
    const float* __restrict__ Wsfc2, const float* __restrict__ bsfc2,
    const float* __restrict__ Wtoa1, const float* __restrict__ btoa1,
    const float* __restrict__ Wtoa2, const float* __restrict__ btoa2,
    const float* __restrict__ Wlat, const float* __restrict__ blat,
    const float* __restrict__ Wout, const float* __restrict__ bout,
    const float* __restrict__ Wsfcout, const float* __restrict__ bsfcout,
    const unsigned short* __restrict__ pw,
    unsigned short* __restrict__ hs1g,
    float* __restrict__ out, float* __restrict__ outsfc, float* __restrict__ latout) {

  __shared__ float g_lds[16 * 772];
  __shared__ __align__(16) unsigned short a_lds[16 * 392];
  __shared__ float misc[16 * 24];
  __shared__ float toa_lds[32];

  const int tid = threadIdx.x;
  const int lane = tid & 63;
  const int wv = tid >> 6;
  const int bid = blockIdx.x;
  const int r0 = bid * 16;

  int erow[6], ecol[6];
  #pragma unroll
  for (int e = 0; e < 6; ++e) { int idx = tid + 512 * e; erow[e] = idx / 192; ecol[e] = idx % 192; }

  if (tid < 384) {
    int r = tid / 24, j = tid % 24;
    misc[tid] = (xsfc[(r0 + r) * 24 + j] - xmean_sca[j]) / xdiv_sca[j];
  }
  __syncthreads();
  if (tid < 32) toa_lds[tid] = misc[(tid >> 1) * 24 + (tid & 1)];

  float c[6];
  #pragma unroll
  for (int e = 0; e < 6; ++e) {
    int row = erow[e], col = ecol[e];
    float a1 = bsfc1[col], a2 = bsfc2[col];
    for (int k = 0; k < 24; ++k) {
      float s = misc[row * 24 + k];
      a1 = fmaf(s, Wsfc1[col * 24 + k], a1);
      a2 = fmaf(s, Wsfc2[col * 24 + k], a2);
    }
    a_lds[row * 392 + col] = f2bf(tanhf_(a1));
    c[e] = tanhf_(a2);
  }

  bf16x8 w1[7][6];
  #pragma unroll
  for (int kk = 0; kk < 7; ++kk)
    #pragma unroll
    for (int nt = 0; nt < 6; ++nt)
      w1[kk][nt] = *(const bf16x8*)&pw[((kk * 48 + wv * 6 + nt) * 64 + lane) * 8];

  const int xr = tid >> 5, xj = tid & 31;
  float xraw = 0.f;
  if (xj < 15)      xraw = __builtin_nontemporal_load(&xlev[((r0 + xr) * 60 + 59) * 15 + xj]);
  else if (xj < 31) xraw = __builtin_nontemporal_load(&hmem[((r0 + xr) * 60 + 59) * 16 + (xj - 15)]);

  for (int l = 59; l >= 0; --l) {
    {
      float v;
      if (xj < 15)      v = (xraw - xmean_lev[l * 15 + xj]) / xdiv_lev[l * 15 + xj];
      else if (xj < 31) v = xraw;
      else              v = 1.0f;
      a_lds[xr * 392 + 192 + xj] = f2bf(v);
    }
    if (l > 0) {
      if (xj < 15)      xraw = __builtin_nontemporal_load(&xlev[((r0 + xr) * 60 + l - 1) * 15 + xj]);
      else if (xj < 31) xraw = __builtin_nontemporal_load(&hmem[((r0 + xr) * 60 + l - 1) * 16 + (xj - 15)]);
    }
    __syncthreads();

    f32x4 acc[6];
    #pragma unroll
    for (int nt = 0; nt < 6; ++nt) acc[nt] = (f32x4){0.f, 0.f, 0.f, 0.f};
    #pragma unroll
    for (int kk = 0; kk < 7; ++kk) {
      const bf16x8 af = *(const bf16x8*)&a_lds[(lane & 15) * 392 + kk * 32 + (lane >> 4) * 8];
      #pragma unroll
      for (int nt = 0; nt < 6; ++nt)
        acc[nt] = __builtin_amdgcn_mfma_f32_16x16x32_bf16(af, w1[kk][nt], acc[nt], 0, 0, 0);
    }
    #pragma unroll
    for (int nt = 0; nt < 6; ++nt)
      #pragma unroll
      for (int q = 0; q < 4; ++q)
        g_lds[((lane >> 4) * 4 + q) * 772 + wv * 96 + nt * 16 + (lane & 15)] = acc[nt][q];
    __syncthreads();

    #pragma unroll
    for (int e = 0; e < 6; ++e) {
      int row = erow[e], col = ecol[e];
      float gi = g_lds[row * 772 + col];
      float gf = g_lds[row * 772 + 192 + col];
      float gg = g_lds[row * 772 + 384 + col];
      float go = g_lds[row * 772 + 576 + col];
      c[e] = sigm(gf) * c[e] + sigm(gi) * tanhf_(gg);
      float hv = sigm(go) * tanhf_(c[e]);
      unsigned short hb = f2bf(hv);
      a_lds[row * 392 + col] = hb;
      __builtin_nontemporal_store(hb, &hs1g[(bid * 60 + l) * 3072 + tid + 512 * e]);
    }
  }

  #pragma unroll
  for (int e = 0; e < 6; ++e) {
    int row = erow[e], col = ecol[e];
    float t0 = toa_lds[row * 2], t1 = toa_lds[row * 2 + 1];
    float a1 = fmaf(t0, Wtoa1[col * 2], fmaf(t1, Wtoa1[col * 2 + 1], btoa1[col]));
    float a2 = fmaf(t0, Wtoa2[col * 2], fmaf(t1, Wtoa2[col * 2 + 1], btoa2[col]));
    a_lds[row * 392 + col] = f2bf(tanhf_(a1));
    c[e] = tanhf_(a2);
  }
  bf16x8 w2[6][6];
  #pragma unroll
  for (int kk = 0; kk < 6; ++kk)
    #pragma unroll
    for (int nt = 0; nt < 6; ++nt)
      w2[kk][nt] = *(const bf16x8*)&pw[((SEG_B2H + kk * 48 + wv * 6 + nt) * 64 + lane) * 8];

  const bf16x8* hs1v = (const bf16x8*)hs1g;
  bf16x8 hv8;
  if (tid < 384) hv8 = __builtin_nontemporal_load(&hs1v[(bid * 60 + 0) * 384 + tid]);

  for (int l = 0; l < 60; ++l) {
    if (tid < 384)
      *(bf16x8*)&a_lds[(tid / 24) * 392 + 192 + (tid % 24) * 8] = hv8;
    if (tid < 384 && l < 59)
      hv8 = __builtin_nontemporal_load(&hs1v[(bid * 60 + l + 1) * 384 + tid]);

    bf16x8 wx0[6], wx1[6];
    #pragma unroll
    for (int nt = 0; nt < 6; ++nt)
      wx0[nt] = *(const bf16x8*)&pw[((SEG_B2X + 0 * 48 + wv * 6 + nt) * 64 + lane) * 8];
    #pragma unroll
    for (int nt = 0; nt < 6; ++nt)
      wx1[nt] = *(const bf16x8*)&pw[((SEG_B2X + 1 * 48 + wv * 6 + nt) * 64 + lane) * 8];

    __syncthreads();

    f32x4 acc[6];
    #pragma unroll
    for (int nt = 0; nt < 6; ++nt) acc[nt] = (f32x4){0.f, 0.f, 0.f, 0.f};

    #pragma unroll
    for (int g = 0; g < 6; ++g) {
      const bf16x8 ah = *(const bf16x8*)&a_lds[(lane & 15) * 392 + g * 32 + (lane >> 4) * 8];
      #pragma unroll
      for (int nt = 0; nt < 6; ++nt)
        acc[nt] = __builtin_amdgcn_mfma_f32_16x16x32_bf16(ah, w2[g][nt], acc[nt], 0, 0, 0);
      const bf16x8 ax = *(const bf16x8*)&a_lds[(lane & 15) * 392 + 192 + g * 32 + (lane >> 4) * 8];
      #pragma unroll
      for (int nt = 0; nt < 6; ++nt)
        acc[nt] = __builtin_amdgcn_mfma_f32_16x16x32_bf16(ax, (g & 1) ? wx1[nt] : wx0[nt], acc[nt], 0, 0, 0);
      if (g < 4) {
        #pragma unroll
        for (int nt = 0; nt < 6; ++nt) {
          bf16x8 nw = *(const bf16x8*)&pw[((SEG_B2X + (g + 2) * 48 + wv * 6 + nt) * 64 + lane) * 8];
          if (g & 1) wx1[nt] = nw; else wx0[nt] = nw;
        }
      }
    }
    #pragma unroll
    for (int nt = 0; nt < 6; ++nt)
      #pragma unroll
      for (int q = 0; q < 4; ++q)
        g_lds[((lane >> 4) * 4 + q) * 772 + wv * 96 + nt * 16 + (lane & 15)] = acc[nt][q];
    __syncthreads();

    #pragma unroll
    for (int e = 0; e < 6; ++e) {
      int row = erow[e], col = ecol[e];
      float gi = g_lds[row * 772 + col]       + b2[col];
      float gf = g_lds[row * 772 + 192 + col] + b2[192 + col];
      float gg = g_lds[row * 772 + 384 + col] + b2[384 + col];
      float go = g_lds[row * 772 + 576 + col] + b2[576 + col];
      c[e] = sigm(gf) * c[e] + sigm(gi) * tanhf_(gg);
      a_lds[row * 392 + col] = f2bf(sigm(go) * tanhf_(c[e]));
    }
    __syncthreads();

    if (tid < 256) {
      int r = tid >> 4, cc = tid & 15;
      float lv = blat[cc];
      for (int k = 0; k < 192; k += 8) {
        #pragma unroll
        for (int jj = 0; jj < 8; ++jj)
          lv = fmaf(bf2f(a_lds[r * 392 + k + jj]), Wlat[cc * 192 + k + jj], lv);
      }
      __builtin_nontemporal_store(lv, &latout[((r0 + r) * 60 + l) * 16 + cc]);
      misc[r * 16 + cc] = lv;
    }
    __syncthreads();
    if (tid < 80) {
      int r = tid / 5, y = tid % 5;
      float ov = bout[y];
      #pragma unroll
      for (int k = 0; k < 16; ++k) ov = fmaf(misc[r * 16 + k], Wout[y * 16 + k], ov);
      __builtin_nontemporal_store(ov / yscale_lev[l * 5 + y], &out[((r0 + r) * 60 + l) * 5 + y]);
    }
  }

  if (tid < 80) {
    int r = tid / 5, y = tid % 5;
    float ov = bsfcout[y];
    for (int k = 0; k < 192; ++k)
      ov = fmaf(bf2f(a_lds[r * 392 + k]), Wsfcout[y * 192 + k], ov);
    outsfc[(r0 + r) * 5 + y] = ov / yscale_sca[y];
  }
}

extern "C" void kernel_launch(void* const* d_in, const int* in_sizes, int n_in,
                              void* d_out, int out_size, void* d_ws, size_t ws_size,
                              hipStream_t stream) {
  (void)in_sizes; (void)n_in; (void)out_size;

  const float* xlev      = (const float*)d_in[0];
  const float* xsfc      = (const float*)d_in[1];
  const float* hmem      = (const float*)d_in[2];
  const float* xmean_lev = (const float*)d_in[3];
  const float* xdiv_lev  = (const float*)d_in[4];
  const float* xmean_sca = (const float*)d_in[5];
  const float* xdiv_sca  = (const float*)d_in[6];
  const float* yscale_lev= (const float*)d_in[7];
  const float* yscale_sca= (const float*)d_in[8];
  const float* Wih1      = (const float*)d_in[9];
  const float* Whh1      = (const float*)d_in[10];
  const float* b1        = (const float*)d_in[11];
  const float* Wih2      = (const float*)d_in[12];
  const float* Whh2      = (const float*)d_in[13];
  const float* b2        = (const float*)d_in[14];
  const float* Wsfc1     = (const float*)d_in[15];
  const float* bsfc1     = (const float*)d_in[16];
  const float* Wsfc2     = (const float*)d_in[17];
  const float* bsfc2     = (const float*)d_in[18];
  const float* Wtoa1     = (const float*)d_in[19];
  const float* btoa1     = (const float*)d_in[20];
  const float* Wtoa2     = (const float*)d_in[21];
  const float* btoa2     = (const float*)d_in[22];
  const float* Wlat      = (const float*)d_in[23];
  const float* blat      = (const float*)d_in[24];
  const float* Wout      = (const float*)d_in[25];
  const float* bout      = (const float*)d_in[26];
  const float* Wsfcout   = (const float*)d_in[27];
  const float* bsfcout   = (const float*)d_in[28];

  unsigned short* pw   = (unsigned short*)d_ws;
  unsigned short* hsg  = (unsigned short*)((char*)d_ws + HS1_OFF);   // hs1, then hs2
  float* cws           = (float*)((char*)d_ws + CWS_OFF);
  float* xg2           = (float*)((char*)d_ws + XG2_OFF);
  float* out    = (float*)d_out;
  float* outsfc = out + (size_t)4096 * 60 * 5;
  float* latout = outsfc + (size_t)4096 * 5;

  // levels per chunk that fit the workspace tail
  long long avail = (long long)ws_size - (long long)XG2_OFF;
  int C = (avail > 0) ? (int)(avail / (long long)XG2_PER_LEVEL) : 0;
  if (C > 60) C = 60;

  hipLaunchKernelGGL(pack_kernel, dim3(PACK_TOTAL / 256), dim3(256), 0, stream,
                     Wih1, Whh1, b1, Wih2, Whh2, pw);

  if (C >= 1) {
    hipLaunchKernelGGL(k1_lstm1, dim3(256), dim3(512), 0, stream,
                       xlev, xsfc, hmem, xmean_lev, xdiv_lev, xmean_sca, xdiv_sca,
                       Wsfc1, bsfc1, Wsfc2, bsfc2, pw, hsg);
    int l0 = 0;
    while (l0 < 60) {
      int Cc = (60 - l0 < C) ? (60 - l0) : C;
      hipLaunchKernelGGL(k2_xg2, dim3(32 * Cc), dim3(512), 0, stream,
                         pw, hsg, b2, xg2, l0, Cc);
      hipLaunchKernelGGL(k3_lstm2, dim3(256), dim3(512), 0, stream,
                         xsfc, xmean_sca, xdiv_sca, Wtoa1, btoa1, Wtoa2, btoa2,
                         pw, xg2, hsg, cws, l0, l0 + Cc, (l0 + Cc < 60) ? 1 : 0);
      l0 += Cc;
    }
    hipLaunchKernelGGL(k4_out, dim3(976), dim3(256), 0, stream,
                       hsg, Wlat, blat, Wout, bout, Wsfcout, bsfcout,
                       yscale_lev, yscale_sca, out, outsfc, latout);
  } else if (ws_size >= (size_t)NEED_MIN) {
    hipLaunchKernelGGL(lstm_main, dim3(256), dim3(512), 0, stream,
                       xlev, xsfc, hmem, xmean_lev, xdiv_lev, xmean_sca, xdiv_sca,
                       yscale_lev, yscale_sca, b2,
                       Wsfc1, bsfc1, Wsfc2, bsfc2, Wtoa1, btoa1, Wtoa2, btoa2,
                       Wlat, blat, Wout, bout, Wsfcout, bsfcout,
                       pw, hsg, out, outsfc, latout);
  }
}